// Round 1
// baseline (1110.796 us; speedup 1.0000x reference)
//
#include <hip/hip_runtime.h>

// Fused attention block: q/k/v = relu(X W + b); A = softmax(qk^T/sqrt(C)); out = relu((A v) FC + b)
// B=8, Lq=Lk=2048, C1=C=512.  All matmuls via bf16 16x16x32 MFMA, fp32 accumulate.
// Verified fragment layouts (learn_hip m89/m91): A-frag A[m=l&15][k=(l>>4)*8+j],
// B-frag B[k=(l>>4)*8+j][n=l&15], C/D row=(l>>4)*4+r, col=l&15.

typedef __attribute__((ext_vector_type(8))) short short8;  // 8 bf16 (4 VGPRs)
typedef __attribute__((ext_vector_type(4))) float f32x4;

#define SEQ 2048
#define CH 512
#define NB 8
#define MTOT (NB * SEQ)   // 16384

__device__ __forceinline__ unsigned short f2bf(float f) {  // fp32 -> bf16 RNE
  unsigned u = __float_as_uint(f);
  u += 0x7fffu + ((u >> 16) & 1u);
  return (unsigned short)(u >> 16);
}

// ---------------- fp32 -> bf16 elementwise (rep, rep1) ----------------
__global__ void cvt_bf16_kernel(const float* __restrict__ in, unsigned short* __restrict__ out) {
  long i = ((long)blockIdx.x * 256 + threadIdx.x) * 8;
  float4 a = *(const float4*)(in + i);
  float4 b = *(const float4*)(in + i + 4);
  ushort4 o0, o1;
  o0.x = f2bf(a.x); o0.y = f2bf(a.y); o0.z = f2bf(a.z); o0.w = f2bf(a.w);
  o1.x = f2bf(b.x); o1.y = f2bf(b.y); o1.z = f2bf(b.z); o1.w = f2bf(b.w);
  *(ushort4*)(out + i) = o0;
  *(ushort4*)(out + i + 4) = o1;
}

// ---------------- W[k][n] fp32 -> Wt[n][k] bf16 (512x512) ----------------
__global__ __launch_bounds__(256) void wtrans_kernel(const float* __restrict__ W,
                                                     unsigned short* __restrict__ Wt) {
  __shared__ __attribute__((aligned(16))) unsigned short tile[64 * 72];
  const int t = threadIdx.x;
  const int k0 = blockIdx.y * 64, n0 = blockIdx.x * 64;
  const int r = t >> 4, cq = (t & 15) * 4;
#pragma unroll
  for (int j = 0; j < 4; ++j) {
    int row = r + 16 * j;  // k index
    float4 v = *(const float4*)&W[(long)(k0 + row) * 512 + n0 + cq];
    tile[row * 72 + cq + 0] = f2bf(v.x);
    tile[row * 72 + cq + 1] = f2bf(v.y);
    tile[row * 72 + cq + 2] = f2bf(v.z);
    tile[row * 72 + cq + 3] = f2bf(v.w);
  }
  __syncthreads();
#pragma unroll
  for (int j = 0; j < 4; ++j) {
    int row = r + 16 * j;  // n index
    ushort4 o;
    o.x = tile[(cq + 0) * 72 + row];
    o.y = tile[(cq + 1) * 72 + row];
    o.z = tile[(cq + 2) * 72 + row];
    o.w = tile[(cq + 3) * 72 + row];
    *(ushort4*)&Wt[(long)(n0 + row) * 512 + k0 + cq] = o;
  }
}

// ---------------- V[b*2048+k][d] bf16 -> Vt[b][d][k] bf16 ----------------
__global__ __launch_bounds__(256) void vtrans_kernel(const unsigned short* __restrict__ V,
                                                     unsigned short* __restrict__ Vt) {
  __shared__ __attribute__((aligned(16))) unsigned short tile[64 * 72];
  const int t = threadIdx.x;
  const int b = blockIdx.z;
  const int kk0 = blockIdx.y * 64;  // seq
  const int d0 = blockIdx.x * 64;   // channel
  const unsigned short* Vb = V + (long)b * SEQ * CH;
  unsigned short* Vtb = Vt + (long)b * CH * SEQ;
  const int r = t >> 4, cq = (t & 15) * 4;
#pragma unroll
  for (int j = 0; j < 4; ++j) {
    int row = r + 16 * j;  // k index
    ushort4 v = *(const ushort4*)&Vb[(long)(kk0 + row) * CH + d0 + cq];
    tile[row * 72 + cq + 0] = v.x;
    tile[row * 72 + cq + 1] = v.y;
    tile[row * 72 + cq + 2] = v.z;
    tile[row * 72 + cq + 3] = v.w;
  }
  __syncthreads();
#pragma unroll
  for (int j = 0; j < 4; ++j) {
    int row = r + 16 * j;  // d index
    ushort4 o;
    o.x = tile[(cq + 0) * 72 + row];
    o.y = tile[(cq + 1) * 72 + row];
    o.z = tile[(cq + 2) * 72 + row];
    o.w = tile[(cq + 3) * 72 + row];
    *(ushort4*)&Vtb[(long)(d0 + row) * SEQ + kk0 + cq] = o;
  }
}

// ---------------- NT GEMM: out[m][n] = relu(A[m][:] . Bt[n][:] + bias[n]) ----------------
// A: [M][512] bf16, Bt: [512][512] bf16 (pre-transposed weight), grid (N/128, M/128), 256 thr.
// LDS stride 56 elems = 112B: 16B-aligned b128 reads, worst 2-way bank alias (free, m136).
template <int OUT_BF16>
__global__ __launch_bounds__(256) void gemm_nt(const unsigned short* __restrict__ A,
                                               const unsigned short* __restrict__ Bt,
                                               const float* __restrict__ bias,
                                               void* __restrict__ outp) {
  __shared__ __attribute__((aligned(16))) unsigned short Al[128 * 56];
  __shared__ __attribute__((aligned(16))) unsigned short Bl[128 * 56];
  const int t = threadIdx.x;
  const int w = t >> 6, l = t & 63;
  const int wr = w >> 1, wc = w & 1;
  const int lr = l & 15, lc = (l >> 4) * 8;
  const long m0 = (long)blockIdx.y * 128, n0 = (long)blockIdx.x * 128;
  const int srow = t >> 2, scol = (t & 3) * 8;  // staging: 4 lanes x 16B = 64B/row
  f32x4 acc[4][4] = {};
  for (int k0 = 0; k0 < CH; k0 += 32) {
#pragma unroll
    for (int j = 0; j < 2; ++j) {
      int r = srow + 64 * j;
      *(short8*)&Al[r * 56 + scol] = *(const short8*)&A[(m0 + r) * CH + k0 + scol];
      *(short8*)&Bl[r * 56 + scol] = *(const short8*)&Bt[(n0 + r) * CH + k0 + scol];
    }
    __syncthreads();
    short8 af[4], bfr[4];
#pragma unroll
    for (int i = 0; i < 4; ++i) {
      af[i]  = *(short8*)&Al[(64 * wr + 16 * i + lr) * 56 + lc];
      bfr[i] = *(short8*)&Bl[(64 * wc + 16 * i + lr) * 56 + lc];
    }
#pragma unroll
    for (int mi = 0; mi < 4; ++mi)
#pragma unroll
      for (int ni = 0; ni < 4; ++ni)
        acc[mi][ni] = __builtin_amdgcn_mfma_f32_16x16x32_bf16(af[mi], bfr[ni], acc[mi][ni], 0, 0, 0);
    __syncthreads();
  }
  float bv[4];
#pragma unroll
  for (int ni = 0; ni < 4; ++ni) bv[ni] = bias[n0 + 64 * wc + 16 * ni + lr];
#pragma unroll
  for (int mi = 0; mi < 4; ++mi)
#pragma unroll
    for (int ni = 0; ni < 4; ++ni)
#pragma unroll
      for (int r = 0; r < 4; ++r) {
        long row = m0 + 64 * wr + 16 * mi + (l >> 4) * 4 + r;
        long col = n0 + 64 * wc + 16 * ni + lr;
        float v = fmaxf(acc[mi][ni][r] + bv[ni], 0.0f);
        if (OUT_BF16) ((unsigned short*)outp)[row * CH + col] = f2bf(v);
        else          ((float*)outp)[row * CH + col] = v;
      }
}

// ---------------- Flash attention (no score materialization) ----------------
// Block: 128 thr = 2 waves, each wave owns 16 q-rows (Q-tile 32). K-tile 128 keys.
// No max-subtraction (logits ~ O(3)); P partial sums combine linearly, divide at end.
__global__ __launch_bounds__(128, 2) void attn_kernel(const unsigned short* __restrict__ Q,
                                                      const unsigned short* __restrict__ Km,
                                                      const unsigned short* __restrict__ Vt,
                                                      unsigned short* __restrict__ O) {
  __shared__ __attribute__((aligned(16))) unsigned short Sb[2][128 * 72];  // K [128][64+8] / Vt [64][128+8]
  __shared__ __attribute__((aligned(16))) unsigned short Pl[2][16 * 136];  // per-wave P strip [16][128+8]
  const int t = threadIdx.x;
  const int w = t >> 6, l = t & 63;
  const int lr = l & 15, lg = l >> 4;
  const int lc0 = lg * 8;
  const int b = blockIdx.y;
  const int q0 = blockIdx.x * 32;
  const unsigned short* Qrow = Q + (long)(b * SEQ + q0 + 16 * w + lr) * CH + lc0;
  const unsigned short* Kb = Km + (long)b * SEQ * CH;
  const unsigned short* Vtb = Vt + (long)b * CH * SEQ;
  const int krow = t >> 3, kcol = (t & 7) * 8;   // K staging: 16 rows/pass, 8 passes
  const int vrow = t >> 4, vcol = (t & 15) * 8;  // Vt staging: 8 rows/pass, 8 passes

  f32x4 acc_o[32] = {};
  float rs[4] = {0.f, 0.f, 0.f, 0.f};

  for (int kt = 0; kt < SEQ; kt += 128) {
    // ---- S = Q K^T over d, chunks of 64 ----
    f32x4 acc_s[8] = {};
#pragma unroll
    for (int j = 0; j < 8; ++j)
      *(short8*)&Sb[0][(krow + 16 * j) * 72 + kcol] =
          *(const short8*)&Kb[(long)(kt + krow + 16 * j) * CH + kcol];
    __syncthreads();
    short8 qa = *(const short8*)&Qrow[0];
    short8 qb = *(const short8*)&Qrow[32];
    for (int c = 0; c < 8; ++c) {
      const int cur = c & 1;
      short8 qa2 = qa, qb2 = qb;
      if (c < 7) {
#pragma unroll
        for (int j = 0; j < 8; ++j)
          *(short8*)&Sb[cur ^ 1][(krow + 16 * j) * 72 + kcol] =
              *(const short8*)&Kb[(long)(kt + krow + 16 * j) * CH + (c + 1) * 64 + kcol];
        qa2 = *(const short8*)&Qrow[(c + 1) * 64];
        qb2 = *(const short8*)&Qrow[(c + 1) * 64 + 32];
      }
#pragma unroll
      for (int s = 0; s < 8; ++s) {
        short8 kf0 = *(short8*)&Sb[cur][(16 * s + lr) * 72 + lc0];
        short8 kf1 = *(short8*)&Sb[cur][(16 * s + lr) * 72 + 32 + lc0];
        acc_s[s] = __builtin_amdgcn_mfma_f32_16x16x32_bf16(qa, kf0, acc_s[s], 0, 0, 0);
        acc_s[s] = __builtin_amdgcn_mfma_f32_16x16x32_bf16(qb, kf1, acc_s[s], 0, 0, 0);
      }
      qa = qa2; qb = qb2;
      __syncthreads();
    }
    // ---- P = exp(S/sqrt(512)); row-sum partials; write P strip (C-layout -> [q][k] LDS) ----
#pragma unroll
    for (int s = 0; s < 8; ++s)
#pragma unroll
      for (int r = 0; r < 4; ++r) {
        float p = exp2f(acc_s[s][r] * 0.06375872f);  // (1/sqrt(512))*log2(e)
        rs[r] += p;
        Pl[w][(lg * 4 + r) * 136 + 16 * s + lr] = f2bf(p);
      }
    __syncthreads();
    short8 pf[4];
#pragma unroll
    for (int cc = 0; cc < 4; ++cc)
      pf[cc] = *(short8*)&Pl[w][lr * 136 + 32 * cc + lc0];
    // ---- O += P V, d-chunks of 64 (Vt[d][k] so k contiguous) ----
#pragma unroll
    for (int j = 0; j < 8; ++j)
      *(short8*)&Sb[0][(vrow + 8 * j) * 136 + vcol] =
          *(const short8*)&Vtb[(long)(vrow + 8 * j) * SEQ + kt + vcol];
    __syncthreads();
    for (int c = 0; c < 8; ++c) {
      const int cur = c & 1;
      if (c < 7) {
#pragma unroll
        for (int j = 0; j < 8; ++j)
          *(short8*)&Sb[cur ^ 1][(vrow + 8 * j) * 136 + vcol] =
              *(const short8*)&Vtb[(long)((c + 1) * 64 + vrow + 8 * j) * SEQ + kt + vcol];
      }
#pragma unroll
      for (int s = 0; s < 4; ++s)
#pragma unroll
        for (int cc = 0; cc < 4; ++cc) {
          short8 vf = *(short8*)&Sb[cur][(16 * s + lr) * 136 + 32 * cc + lc0];
          acc_o[c * 4 + s] =
              __builtin_amdgcn_mfma_f32_16x16x32_bf16(pf[cc], vf, acc_o[c * 4 + s], 0, 0, 0);
        }
      __syncthreads();
    }
  }
  // ---- finalize: reduce row-sums across the 16 lanes holding each row, divide, store ----
#pragma unroll
  for (int off = 1; off < 16; off <<= 1)
#pragma unroll
    for (int r = 0; r < 4; ++r) rs[r] += __shfl_xor(rs[r], off, 16);
  float inv[4];
#pragma unroll
  for (int r = 0; r < 4; ++r) inv[r] = 1.0f / rs[r];
  unsigned short* Ob = O + (long)(b * SEQ + q0 + 16 * w) * CH;
#pragma unroll
  for (int dt = 0; dt < 32; ++dt)
#pragma unroll
    for (int r = 0; r < 4; ++r)
      Ob[(long)(lg * 4 + r) * CH + 16 * dt + lr] = f2bf(acc_o[dt][r] * inv[r]);
}

extern "C" void kernel_launch(void* const* d_in, const int* in_sizes, int n_in,
                              void* d_out, int out_size, void* d_ws, size_t ws_size,
                              hipStream_t stream) {
  const float* rep  = (const float*)d_in[0];
  const float* rep1 = (const float*)d_in[1];
  const float* Wq_w = (const float*)d_in[2];
  const float* Wq_b = (const float*)d_in[3];
  const float* Wk_w = (const float*)d_in[4];
  const float* Wk_b = (const float*)d_in[5];
  const float* Wv_w = (const float*)d_in[6];
  const float* Wv_b = (const float*)d_in[7];
  const float* FC_w = (const float*)d_in[8];
  const float* FC_b = (const float*)d_in[9];
  float* out = (float*)d_out;
  char* ws = (char*)d_ws;

  const size_t SZB = (size_t)MTOT * CH * 2;  // 16 MB per bf16 [16384][512] buffer
  const size_t need = 6 * SZB + 4 * (size_t)512 * 512 * 2;
  if (ws_size < need) return;  // visible failure rather than OOB scribble

  unsigned short* Qb    = (unsigned short*)(ws + 0 * SZB);
  unsigned short* Kbuf  = (unsigned short*)(ws + 1 * SZB);
  unsigned short* Vbuf  = (unsigned short*)(ws + 2 * SZB);  // reused as attn output after vtrans
  unsigned short* Vtb   = (unsigned short*)(ws + 3 * SZB);
  unsigned short* repb  = (unsigned short*)(ws + 4 * SZB);
  unsigned short* rep1b = (unsigned short*)(ws + 5 * SZB);
  unsigned short* Wtq   = (unsigned short*)(ws + 6 * SZB);
  unsigned short* Wtk   = Wtq + 512 * 512;
  unsigned short* Wtv   = Wtk + 512 * 512;
  unsigned short* Wtf   = Wtv + 512 * 512;

  cvt_bf16_kernel<<<4096, 256, 0, stream>>>(rep, repb);
  cvt_bf16_kernel<<<4096, 256, 0, stream>>>(rep1, rep1b);
  wtrans_kernel<<<dim3(8, 8), 256, 0, stream>>>(Wq_w, Wtq);
  wtrans_kernel<<<dim3(8, 8), 256, 0, stream>>>(Wk_w, Wtk);
  wtrans_kernel<<<dim3(8, 8), 256, 0, stream>>>(Wv_w, Wtv);
  wtrans_kernel<<<dim3(8, 8), 256, 0, stream>>>(FC_w, Wtf);

  gemm_nt<1><<<dim3(4, 128), 256, 0, stream>>>(repb,  Wtq, Wq_b, Qb);
  gemm_nt<1><<<dim3(4, 128), 256, 0, stream>>>(rep1b, Wtk, Wk_b, Kbuf);
  gemm_nt<1><<<dim3(4, 128), 256, 0, stream>>>(rep1b, Wtv, Wv_b, Vbuf);

  vtrans_kernel<<<dim3(8, 32, 8), 256, 0, stream>>>(Vbuf, Vtb);

  attn_kernel<<<dim3(64, 8), 128, 0, stream>>>(Qb, Kbuf, Vtb, Vbuf);  // O -> Vbuf (V dead)

  gemm_nt<0><<<dim3(4, 128), 256, 0, stream>>>(Vbuf, Wtf, FC_b, (void*)out);
}

// Round 2
// 360.411 us; speedup vs baseline: 3.0820x; 3.0820x over previous
//
#include <hip/hip_runtime.h>

// Fused attention block: q/k/v = relu(X W + b); A = softmax(qk^T/sqrt(C)); out = relu((A v) FC + b)
// B=8, Lq=Lk=2048, C1=C=512.  All matmuls via bf16 16x16x32 MFMA, fp32 accumulate.
// R1->R2: flash-style attn (2 blocks/CU, MfmaUtil 3%) replaced by GEMM-shaped
// QK^T (+exp epilogue + rowsum atomics, 2048 blocks) and PV (+1/rowsum epilogue),
// materializing P bf16 (64 MiB, ~20us HBM) to buy occupancy.

typedef __attribute__((ext_vector_type(8))) short short8;  // 8 bf16 (4 VGPRs)
typedef __attribute__((ext_vector_type(4))) float f32x4;

#define SEQ 2048
#define CH 512
#define NB 8
#define MTOT (NB * SEQ)   // 16384

__device__ __forceinline__ unsigned short f2bf(float f) {  // fp32 -> bf16 RNE
  unsigned u = __float_as_uint(f);
  u += 0x7fffu + ((u >> 16) & 1u);
  return (unsigned short)(u >> 16);
}

// ---------------- fp32 -> bf16 elementwise (rep, rep1) ----------------
__global__ void cvt_bf16_kernel(const float* __restrict__ in, unsigned short* __restrict__ out) {
  long i = ((long)blockIdx.x * 256 + threadIdx.x) * 8;
  float4 a = *(const float4*)(in + i);
  float4 b = *(const float4*)(in + i + 4);
  ushort4 o0, o1;
  o0.x = f2bf(a.x); o0.y = f2bf(a.y); o0.z = f2bf(a.z); o0.w = f2bf(a.w);
  o1.x = f2bf(b.x); o1.y = f2bf(b.y); o1.z = f2bf(b.z); o1.w = f2bf(b.w);
  *(ushort4*)(out + i) = o0;
  *(ushort4*)(out + i + 4) = o1;
}

// ---------------- W[k][n] fp32 -> Wt[n][k] bf16 (512x512) ----------------
__global__ __launch_bounds__(256) void wtrans_kernel(const float* __restrict__ W,
                                                     unsigned short* __restrict__ Wt) {
  __shared__ __attribute__((aligned(16))) unsigned short tile[64 * 72];
  const int t = threadIdx.x;
  const int k0 = blockIdx.y * 64, n0 = blockIdx.x * 64;
  const int r = t >> 4, cq = (t & 15) * 4;
#pragma unroll
  for (int j = 0; j < 4; ++j) {
    int row = r + 16 * j;  // k index
    float4 v = *(const float4*)&W[(long)(k0 + row) * 512 + n0 + cq];
    tile[row * 72 + cq + 0] = f2bf(v.x);
    tile[row * 72 + cq + 1] = f2bf(v.y);
    tile[row * 72 + cq + 2] = f2bf(v.z);
    tile[row * 72 + cq + 3] = f2bf(v.w);
  }
  __syncthreads();
#pragma unroll
  for (int j = 0; j < 4; ++j) {
    int row = r + 16 * j;  // n index
    ushort4 o;
    o.x = tile[(cq + 0) * 72 + row];
    o.y = tile[(cq + 1) * 72 + row];
    o.z = tile[(cq + 2) * 72 + row];
    o.w = tile[(cq + 3) * 72 + row];
    *(ushort4*)&Wt[(long)(n0 + row) * 512 + k0 + cq] = o;
  }
}

// ---------------- V[b*2048+k][d] bf16 -> Vt[b][d][k] bf16 ----------------
__global__ __launch_bounds__(256) void vtrans_kernel(const unsigned short* __restrict__ V,
                                                     unsigned short* __restrict__ Vt) {
  __shared__ __attribute__((aligned(16))) unsigned short tile[64 * 72];
  const int t = threadIdx.x;
  const int b = blockIdx.z;
  const int kk0 = blockIdx.y * 64;  // seq
  const int d0 = blockIdx.x * 64;   // channel
  const unsigned short* Vb = V + (long)b * SEQ * CH;
  unsigned short* Vtb = Vt + (long)b * CH * SEQ;
  const int r = t >> 4, cq = (t & 15) * 4;
#pragma unroll
  for (int j = 0; j < 4; ++j) {
    int row = r + 16 * j;  // k index
    ushort4 v = *(const ushort4*)&Vb[(long)(kk0 + row) * CH + d0 + cq];
    tile[row * 72 + cq + 0] = v.x;
    tile[row * 72 + cq + 1] = v.y;
    tile[row * 72 + cq + 2] = v.z;
    tile[row * 72 + cq + 3] = v.w;
  }
  __syncthreads();
#pragma unroll
  for (int j = 0; j < 4; ++j) {
    int row = r + 16 * j;  // d index
    ushort4 o;
    o.x = tile[(cq + 0) * 72 + row];
    o.y = tile[(cq + 1) * 72 + row];
    o.z = tile[(cq + 2) * 72 + row];
    o.w = tile[(cq + 3) * 72 + row];
    *(ushort4*)&Vtb[(long)(d0 + row) * SEQ + kk0 + cq] = o;
  }
}

// ---------------- Generic batched NT GEMM, 128x128 tile, 4 waves ----------------
// out[m][n] = EPI(sum_k A[m][k] * Bt[n][k])
// EPI 0: relu(acc+bias[n]) -> fp32     (FC)
// EPI 1: relu(acc+bias[n]) -> bf16     (q/k/v projections)
// EPI 2: exp2(acc*scale)   -> bf16 P, rowsum[m] += sum_n p  (QK^T)
// EPI 3: acc / rowsum[m]   -> bf16     (P.V)
// LDS stride 56 elems = 112B: 16B-aligned b128 reads, worst 2-way bank alias (free, m136).
template <int EPI>
__global__ __launch_bounds__(256) void gemm_nt(const unsigned short* __restrict__ A,
                                               long sAb, int lda,
                                               const unsigned short* __restrict__ Bt,
                                               long sBb, int ldb,
                                               const float* __restrict__ bias,
                                               float* __restrict__ rowsum, long sRb,
                                               void* __restrict__ outp, long sOb, int ldo,
                                               int K) {
  __shared__ __attribute__((aligned(16))) unsigned short Al[128 * 56];
  __shared__ __attribute__((aligned(16))) unsigned short Bl[128 * 56];
  const int t = threadIdx.x;
  const int w = t >> 6, l = t & 63;
  const int wr = w >> 1, wc = w & 1;
  const int lr = l & 15, lg = l >> 4, lc = lg * 8;
  const int bz = blockIdx.z;
  A += (long)bz * sAb;
  Bt += (long)bz * sBb;
  const long m0 = (long)blockIdx.y * 128, n0 = (long)blockIdx.x * 128;
  const int srow = t >> 2, scol = (t & 3) * 8;  // staging: 4 lanes x 16B = 64B/row
  f32x4 acc[4][4] = {};
  for (int k0 = 0; k0 < K; k0 += 32) {
#pragma unroll
    for (int j = 0; j < 2; ++j) {
      int r = srow + 64 * j;
      *(short8*)&Al[r * 56 + scol] = *(const short8*)&A[(m0 + r) * (long)lda + k0 + scol];
      *(short8*)&Bl[r * 56 + scol] = *(const short8*)&Bt[(n0 + r) * (long)ldb + k0 + scol];
    }
    __syncthreads();
    short8 af[4], bfr[4];
#pragma unroll
    for (int i = 0; i < 4; ++i) {
      af[i]  = *(short8*)&Al[(64 * wr + 16 * i + lr) * 56 + lc];
      bfr[i] = *(short8*)&Bl[(64 * wc + 16 * i + lr) * 56 + lc];
    }
#pragma unroll
    for (int mi = 0; mi < 4; ++mi)
#pragma unroll
      for (int ni = 0; ni < 4; ++ni)
        acc[mi][ni] = __builtin_amdgcn_mfma_f32_16x16x32_bf16(af[mi], bfr[ni], acc[mi][ni], 0, 0, 0);
    __syncthreads();
  }

  if (EPI == 0 || EPI == 1) {
    float bv[4];
#pragma unroll
    for (int ni = 0; ni < 4; ++ni) bv[ni] = bias[n0 + 64 * wc + 16 * ni + lr];
#pragma unroll
    for (int mi = 0; mi < 4; ++mi)
#pragma unroll
      for (int ni = 0; ni < 4; ++ni)
#pragma unroll
        for (int r = 0; r < 4; ++r) {
          long row = m0 + 64 * wr + 16 * mi + lg * 4 + r;
          long col = n0 + 64 * wc + 16 * ni + lr;
          float v = fmaxf(acc[mi][ni][r] + bv[ni], 0.0f);
          if (EPI == 1) ((unsigned short*)outp)[(long)bz * sOb + row * ldo + col] = f2bf(v);
          else          ((float*)outp)[(long)bz * sOb + row * ldo + col] = v;
        }
  } else if (EPI == 2) {
    unsigned short* P = (unsigned short*)outp + (long)bz * sOb;
    float* rs = rowsum + (long)bz * sRb;
    float rsum[4][4] = {};
#pragma unroll
    for (int mi = 0; mi < 4; ++mi)
#pragma unroll
      for (int ni = 0; ni < 4; ++ni)
#pragma unroll
        for (int r = 0; r < 4; ++r) {
          long row = m0 + 64 * wr + 16 * mi + lg * 4 + r;
          long col = n0 + 64 * wc + 16 * ni + lr;
          float p = exp2f(acc[mi][ni][r] * 0.06375872f);  // (1/sqrt(512))*log2(e)
          unsigned short pb = f2bf(p);
          P[row * (long)ldo + col] = pb;
          rsum[mi][r] += __uint_as_float((unsigned)pb << 16);  // sum what PV will see
        }
    // reduce over the 16 lanes (lr) that share each row
#pragma unroll
    for (int off = 1; off < 16; off <<= 1)
#pragma unroll
      for (int mi = 0; mi < 4; ++mi)
#pragma unroll
        for (int r = 0; r < 4; ++r) rsum[mi][r] += __shfl_xor(rsum[mi][r], off);
    if (lr == 0) {
#pragma unroll
      for (int mi = 0; mi < 4; ++mi)
#pragma unroll
        for (int r = 0; r < 4; ++r)
          atomicAdd(&rs[m0 + 64 * wr + 16 * mi + lg * 4 + r], rsum[mi][r]);
    }
  } else {  // EPI == 3
    unsigned short* O = (unsigned short*)outp + (long)bz * sOb;
    const float* rs = rowsum + (long)bz * sRb;
    float inv[4][4];
#pragma unroll
    for (int mi = 0; mi < 4; ++mi)
#pragma unroll
      for (int r = 0; r < 4; ++r)
        inv[mi][r] = 1.0f / rs[m0 + 64 * wr + 16 * mi + lg * 4 + r];
#pragma unroll
    for (int mi = 0; mi < 4; ++mi)
#pragma unroll
      for (int ni = 0; ni < 4; ++ni)
#pragma unroll
        for (int r = 0; r < 4; ++r) {
          long row = m0 + 64 * wr + 16 * mi + lg * 4 + r;
          long col = n0 + 64 * wc + 16 * ni + lr;
          O[row * (long)ldo + col] = f2bf(acc[mi][ni][r] * inv[mi][r]);
        }
  }
}

extern "C" void kernel_launch(void* const* d_in, const int* in_sizes, int n_in,
                              void* d_out, int out_size, void* d_ws, size_t ws_size,
                              hipStream_t stream) {
  const float* rep  = (const float*)d_in[0];
  const float* rep1 = (const float*)d_in[1];
  const float* Wq_w = (const float*)d_in[2];
  const float* Wq_b = (const float*)d_in[3];
  const float* Wk_w = (const float*)d_in[4];
  const float* Wk_b = (const float*)d_in[5];
  const float* Wv_w = (const float*)d_in[6];
  const float* Wv_b = (const float*)d_in[7];
  const float* FC_w = (const float*)d_in[8];
  const float* FC_b = (const float*)d_in[9];
  float* out = (float*)d_out;
  char* ws = (char*)d_ws;

  const size_t SZB = (size_t)MTOT * CH * 2;             // 16 MiB bf16 [16384][512]
  const size_t SZP = (size_t)NB * SEQ * SEQ * 2;        // 64 MiB bf16 P
  const size_t SZR = (size_t)MTOT * 4;                  // 64 KiB rowsum
  const size_t need = 6 * SZB + 4 * (size_t)512 * 512 * 2 + SZP + SZR;
  if (ws_size < need) return;  // visible failure rather than OOB scribble

  unsigned short* Qb    = (unsigned short*)(ws + 0 * SZB);
  unsigned short* Kbuf  = (unsigned short*)(ws + 1 * SZB);
  unsigned short* Vbuf  = (unsigned short*)(ws + 2 * SZB);  // reused as attn O after vtrans
  unsigned short* Vtb   = (unsigned short*)(ws + 3 * SZB);
  unsigned short* repb  = (unsigned short*)(ws + 4 * SZB);
  unsigned short* rep1b = (unsigned short*)(ws + 5 * SZB);
  unsigned short* Wtq   = (unsigned short*)(ws + 6 * SZB);
  unsigned short* Wtk   = Wtq + 512 * 512;
  unsigned short* Wtv   = Wtk + 512 * 512;
  unsigned short* Wtf   = Wtv + 512 * 512;
  unsigned short* Pbuf  = (unsigned short*)(ws + 6 * SZB + 4 * (size_t)512 * 512 * 2);
  float*          rowsum = (float*)((char*)Pbuf + SZP);

  hipMemsetAsync(rowsum, 0, SZR, stream);

  cvt_bf16_kernel<<<4096, 256, 0, stream>>>(rep, repb);
  cvt_bf16_kernel<<<4096, 256, 0, stream>>>(rep1, rep1b);
  wtrans_kernel<<<dim3(8, 8), 256, 0, stream>>>(Wq_w, Wtq);
  wtrans_kernel<<<dim3(8, 8), 256, 0, stream>>>(Wk_w, Wtk);
  wtrans_kernel<<<dim3(8, 8), 256, 0, stream>>>(Wv_w, Wtv);
  wtrans_kernel<<<dim3(8, 8), 256, 0, stream>>>(FC_w, Wtf);

  // projections: [16384,512] x [512,512]^T
  gemm_nt<1><<<dim3(4, 128, 1), 256, 0, stream>>>(repb, 0, CH, Wtq, 0, CH, Wq_b,
                                                  nullptr, 0, Qb, 0, CH, CH);
  gemm_nt<1><<<dim3(4, 128, 1), 256, 0, stream>>>(rep1b, 0, CH, Wtk, 0, CH, Wk_b,
                                                  nullptr, 0, Kbuf, 0, CH, CH);
  gemm_nt<1><<<dim3(4, 128, 1), 256, 0, stream>>>(rep1b, 0, CH, Wtv, 0, CH, Wv_b,
                                                  nullptr, 0, Vbuf, 0, CH, CH);

  vtrans_kernel<<<dim3(8, 32, 8), 256, 0, stream>>>(Vbuf, Vtb);

  // P = exp(Q K^T / sqrt(C)) per batch: [2048,512] x [2048,512]^T -> [2048,2048]
  gemm_nt<2><<<dim3(16, 16, 8), 256, 0, stream>>>(Qb, (long)SEQ * CH, CH,
                                                  Kbuf, (long)SEQ * CH, CH, nullptr,
                                                  rowsum, SEQ,
                                                  Pbuf, (long)SEQ * SEQ, SEQ, CH);

  // O = (P / rowsum) V: [2048,2048] x Vt[512,2048]^T -> [2048,512]  (O -> Vbuf, V dead)
  gemm_nt<3><<<dim3(4, 16, 8), 256, 0, stream>>>(Pbuf, (long)SEQ * SEQ, SEQ,
                                                 Vtb, (long)CH * SEQ, SEQ, nullptr,
                                                 rowsum, SEQ,
                                                 Vbuf, (long)SEQ * CH, CH, SEQ);

  // FC + relu -> fp32 out
  gemm_nt<0><<<dim3(4, 128, 1), 256, 0, stream>>>(Vbuf, 0, CH, Wtf, 0, CH, FC_b,
                                                  nullptr, 0, out, 0, CH, CH);
}

// Round 3
// 324.728 us; speedup vs baseline: 3.4207x; 1.1099x over previous
//
#include <hip/hip_runtime.h>

// Fused attention block: q/k/v = relu(X W + b); A = softmax(qk^T/sqrt(C)); out = relu((A v) FC + b)
// B=8, Lq=Lk=2048, C1=C=512.  All matmuls via bf16 16x16x32 MFMA, fp32 accumulate.
// R2->R3: gemm_nt staging switched to global_load_lds width=16 (m93->m97 lever, 1.69x),
// unpadded LDS [row][32] (16KB/block), compile-time lda/ldb/ldo/K (kills runtime 64-bit
// addr math), fused wtrans x4 and cvt x2 launches.

typedef __attribute__((ext_vector_type(8))) short short8;  // 8 bf16 (4 VGPRs)
typedef __attribute__((ext_vector_type(4))) float f32x4;

#define SEQ 2048
#define CH 512
#define NB 8
#define MTOT (NB * SEQ)   // 16384

// async global->LDS, 16B/lane; LDS dest = wave-uniform base + lane*16 (m104/m108)
#define GLDS16(gp, lp)                                                                  \
  __builtin_amdgcn_global_load_lds((const __attribute__((address_space(1))) void*)(gp), \
                                   (__attribute__((address_space(3))) void*)(lp), 16, 0, 0)

__device__ __forceinline__ unsigned short f2bf(float f) {  // fp32 -> bf16 RNE
  unsigned u = __float_as_uint(f);
  u += 0x7fffu + ((u >> 16) & 1u);
  return (unsigned short)(u >> 16);
}

// ---------------- fp32 -> bf16 elementwise: rep (4096 blocks) then rep1 ----------------
__global__ void cvt_bf16_kernel(const float* __restrict__ in0, unsigned short* __restrict__ out0,
                                const float* __restrict__ in1, unsigned short* __restrict__ out1) {
  int blk = blockIdx.x;
  const float* in = (blk < 4096) ? in0 : in1;
  unsigned short* out = (blk < 4096) ? out0 : out1;
  blk &= 4095;
  long i = ((long)blk * 256 + threadIdx.x) * 8;
  float4 a = *(const float4*)(in + i);
  float4 b = *(const float4*)(in + i + 4);
  ushort4 o0, o1;
  o0.x = f2bf(a.x); o0.y = f2bf(a.y); o0.z = f2bf(a.z); o0.w = f2bf(a.w);
  o1.x = f2bf(b.x); o1.y = f2bf(b.y); o1.z = f2bf(b.z); o1.w = f2bf(b.w);
  *(ushort4*)(out + i) = o0;
  *(ushort4*)(out + i + 4) = o1;
}

// ---------------- W[k][n] fp32 -> Wt[n][k] bf16, 4 weights in one dispatch ----------------
__global__ __launch_bounds__(256) void wtrans_kernel(const float* __restrict__ W0,
                                                     const float* __restrict__ W1,
                                                     const float* __restrict__ W2,
                                                     const float* __restrict__ W3,
                                                     unsigned short* __restrict__ Wt) {
  __shared__ __attribute__((aligned(16))) unsigned short tile[64 * 72];
  const int z = blockIdx.z;
  const float* W = (z == 0) ? W0 : (z == 1) ? W1 : (z == 2) ? W2 : W3;
  unsigned short* Wtz = Wt + (long)z * 512 * 512;
  const int t = threadIdx.x;
  const int k0 = blockIdx.y * 64, n0 = blockIdx.x * 64;
  const int r = t >> 4, cq = (t & 15) * 4;
#pragma unroll
  for (int j = 0; j < 4; ++j) {
    int row = r + 16 * j;  // k index
    float4 v = *(const float4*)&W[(long)(k0 + row) * 512 + n0 + cq];
    tile[row * 72 + cq + 0] = f2bf(v.x);
    tile[row * 72 + cq + 1] = f2bf(v.y);
    tile[row * 72 + cq + 2] = f2bf(v.z);
    tile[row * 72 + cq + 3] = f2bf(v.w);
  }
  __syncthreads();
#pragma unroll
  for (int j = 0; j < 4; ++j) {
    int row = r + 16 * j;  // n index
    ushort4 o;
    o.x = tile[(cq + 0) * 72 + row];
    o.y = tile[(cq + 1) * 72 + row];
    o.z = tile[(cq + 2) * 72 + row];
    o.w = tile[(cq + 3) * 72 + row];
    *(ushort4*)&Wtz[(long)(n0 + row) * 512 + k0 + cq] = o;
  }
}

// ---------------- V[b*2048+k][d] bf16 -> Vt[b][d][k] bf16 ----------------
__global__ __launch_bounds__(256) void vtrans_kernel(const unsigned short* __restrict__ V,
                                                     unsigned short* __restrict__ Vt) {
  __shared__ __attribute__((aligned(16))) unsigned short tile[64 * 72];
  const int t = threadIdx.x;
  const int b = blockIdx.z;
  const int kk0 = blockIdx.y * 64;  // seq
  const int d0 = blockIdx.x * 64;   // channel
  const unsigned short* Vb = V + (long)b * SEQ * CH;
  unsigned short* Vtb = Vt + (long)b * CH * SEQ;
  const int r = t >> 4, cq = (t & 15) * 4;
#pragma unroll
  for (int j = 0; j < 4; ++j) {
    int row = r + 16 * j;  // k index
    ushort4 v = *(const ushort4*)&Vb[(long)(kk0 + row) * CH + d0 + cq];
    tile[row * 72 + cq + 0] = v.x;
    tile[row * 72 + cq + 1] = v.y;
    tile[row * 72 + cq + 2] = v.z;
    tile[row * 72 + cq + 3] = v.w;
  }
  __syncthreads();
#pragma unroll
  for (int j = 0; j < 4; ++j) {
    int row = r + 16 * j;  // d index
    ushort4 o;
    o.x = tile[(cq + 0) * 72 + row];
    o.y = tile[(cq + 1) * 72 + row];
    o.z = tile[(cq + 2) * 72 + row];
    o.w = tile[(cq + 3) * 72 + row];
    *(ushort4*)&Vtb[(long)(d0 + row) * SEQ + kk0 + cq] = o;
  }
}

// ---------------- Generic batched NT GEMM, 128x128 tile, 4 waves ----------------
// out[m][n] = EPI(sum_k A[m][k] * Bt[n][k])
// EPI 0: relu(acc+bias[n]) -> fp32     (FC)
// EPI 1: relu(acc+bias[n]) -> bf16     (q/k/v projections)
// EPI 2: exp2(acc*scale)   -> bf16 P, rowsum[m] += sum_n p  (QK^T)
// EPI 3: acc / rowsum[m]   -> bf16     (P.V)
// Staging: global_load_lds dwordx4; LDS [128 rows][32 k-els], no padding (wave-uniform
// base + lane*16B constraint).  16 KB LDS/block.
template <int EPI, int LDA, int LDB, int LDO, int K>
__global__ __launch_bounds__(256) void gemm_nt(const unsigned short* __restrict__ A, long sAb,
                                               const unsigned short* __restrict__ Bt, long sBb,
                                               const float* __restrict__ bias,
                                               float* __restrict__ rowsum, long sRb,
                                               void* __restrict__ outp, long sOb) {
  __shared__ __attribute__((aligned(16))) unsigned short Al[128 * 32];
  __shared__ __attribute__((aligned(16))) unsigned short Bl[128 * 32];
  const int t = threadIdx.x;
  const int w = t >> 6, l = t & 63;
  const int wr = w >> 1, wc = w & 1;
  const int lr = l & 15, lg = l >> 4, lc = lg * 8;
  const int bz = blockIdx.z;
  const long m0 = (long)blockIdx.y * 128, n0 = (long)blockIdx.x * 128;
  // staging: wave w stages A rows [32w,32w+32) and B rows [32w,32w+32), 16 rows/instr,
  // lane l -> (row 32w+16j+(l>>2), k-chunk (l&3)*8)
  const int srow = 32 * w + (l >> 2);
  const int scol = (l & 3) * 8;
  const unsigned short* ga = A + bz * sAb + (long)(m0 + srow) * LDA + scol;
  const unsigned short* gb = Bt + bz * sBb + (long)(n0 + srow) * LDB + scol;
  unsigned short* la = &Al[(32 * w) * 32];  // wave-uniform LDS bases
  unsigned short* lb = &Bl[(32 * w) * 32];

  f32x4 acc[4][4] = {};
  for (int k0 = 0; k0 < K; k0 += 32) {
    GLDS16(ga, la);
    GLDS16(ga + 16 * LDA, la + 16 * 32);
    GLDS16(gb, lb);
    GLDS16(gb + 16 * LDB, lb + 16 * 32);
    ga += 32; gb += 32;
    __syncthreads();
    short8 af[4], bfr[4];
#pragma unroll
    for (int i = 0; i < 4; ++i) {
      af[i]  = *(short8*)&Al[(64 * wr + 16 * i + lr) * 32 + lc];
      bfr[i] = *(short8*)&Bl[(64 * wc + 16 * i + lr) * 32 + lc];
    }
#pragma unroll
    for (int mi = 0; mi < 4; ++mi)
#pragma unroll
      for (int ni = 0; ni < 4; ++ni)
        acc[mi][ni] = __builtin_amdgcn_mfma_f32_16x16x32_bf16(af[mi], bfr[ni], acc[mi][ni], 0, 0, 0);
    __syncthreads();
  }

  if (EPI == 0 || EPI == 1) {
    float bv[4];
#pragma unroll
    for (int ni = 0; ni < 4; ++ni) bv[ni] = bias[n0 + 64 * wc + 16 * ni + lr];
#pragma unroll
    for (int mi = 0; mi < 4; ++mi)
#pragma unroll
      for (int ni = 0; ni < 4; ++ni)
#pragma unroll
        for (int r = 0; r < 4; ++r) {
          long row = m0 + 64 * wr + 16 * mi + lg * 4 + r;
          long col = n0 + 64 * wc + 16 * ni + lr;
          float v = fmaxf(acc[mi][ni][r] + bv[ni], 0.0f);
          if (EPI == 1) ((unsigned short*)outp)[bz * sOb + row * LDO + col] = f2bf(v);
          else          ((float*)outp)[bz * sOb + row * LDO + col] = v;
        }
  } else if (EPI == 2) {
    unsigned short* P = (unsigned short*)outp + bz * sOb;
    float* rs = rowsum + bz * sRb;
    float rsum[4][4] = {};
#pragma unroll
    for (int mi = 0; mi < 4; ++mi)
#pragma unroll
      for (int ni = 0; ni < 4; ++ni)
#pragma unroll
        for (int r = 0; r < 4; ++r) {
          long row = m0 + 64 * wr + 16 * mi + lg * 4 + r;
          long col = n0 + 64 * wc + 16 * ni + lr;
          float p = exp2f(acc[mi][ni][r] * 0.06375872f);  // (1/sqrt(512))*log2(e)
          unsigned short pb = f2bf(p);
          P[row * LDO + col] = pb;
          rsum[mi][r] += __uint_as_float((unsigned)pb << 16);  // sum what PV will see
        }
    // reduce over the 16 lanes (lr) that share each row
#pragma unroll
    for (int off = 1; off < 16; off <<= 1)
#pragma unroll
      for (int mi = 0; mi < 4; ++mi)
#pragma unroll
        for (int r = 0; r < 4; ++r) rsum[mi][r] += __shfl_xor(rsum[mi][r], off);
    if (lr == 0) {
#pragma unroll
      for (int mi = 0; mi < 4; ++mi)
#pragma unroll
        for (int r = 0; r < 4; ++r)
          atomicAdd(&rs[m0 + 64 * wr + 16 * mi + lg * 4 + r], rsum[mi][r]);
    }
  } else {  // EPI == 3
    unsigned short* O = (unsigned short*)outp + bz * sOb;
    const float* rs = rowsum + bz * sRb;
    float inv[4][4];
#pragma unroll
    for (int mi = 0; mi < 4; ++mi)
#pragma unroll
      for (int r = 0; r < 4; ++r)
        inv[mi][r] = 1.0f / rs[m0 + 64 * wr + 16 * mi + lg * 4 + r];
#pragma unroll
    for (int mi = 0; mi < 4; ++mi)
#pragma unroll
      for (int ni = 0; ni < 4; ++ni)
#pragma unroll
        for (int r = 0; r < 4; ++r) {
          long row = m0 + 64 * wr + 16 * mi + lg * 4 + r;
          long col = n0 + 64 * wc + 16 * ni + lr;
          O[row * LDO + col] = f2bf(acc[mi][ni][r] * inv[mi][r]);
        }
  }
}

extern "C" void kernel_launch(void* const* d_in, const int* in_sizes, int n_in,
                              void* d_out, int out_size, void* d_ws, size_t ws_size,
                              hipStream_t stream) {
  const float* rep  = (const float*)d_in[0];
  const float* rep1 = (const float*)d_in[1];
  const float* Wq_w = (const float*)d_in[2];
  const float* Wq_b = (const float*)d_in[3];
  const float* Wk_w = (const float*)d_in[4];
  const float* Wk_b = (const float*)d_in[5];
  const float* Wv_w = (const float*)d_in[6];
  const float* Wv_b = (const float*)d_in[7];
  const float* FC_w = (const float*)d_in[8];
  const float* FC_b = (const float*)d_in[9];
  float* out = (float*)d_out;
  char* ws = (char*)d_ws;

  const size_t SZB = (size_t)MTOT * CH * 2;             // 16 MiB bf16 [16384][512]
  const size_t SZP = (size_t)NB * SEQ * SEQ * 2;        // 64 MiB bf16 P
  const size_t SZR = (size_t)MTOT * 4;                  // 64 KiB rowsum
  const size_t need = 6 * SZB + 4 * (size_t)512 * 512 * 2 + SZP + SZR;
  if (ws_size < need) return;  // visible failure rather than OOB scribble

  unsigned short* Qb    = (unsigned short*)(ws + 0 * SZB);
  unsigned short* Kbuf  = (unsigned short*)(ws + 1 * SZB);
  unsigned short* Vbuf  = (unsigned short*)(ws + 2 * SZB);  // reused as attn O after vtrans
  unsigned short* Vtb   = (unsigned short*)(ws + 3 * SZB);
  unsigned short* repb  = (unsigned short*)(ws + 4 * SZB);
  unsigned short* rep1b = (unsigned short*)(ws + 5 * SZB);
  unsigned short* Wt4   = (unsigned short*)(ws + 6 * SZB);  // Wtq|Wtk|Wtv|Wtf
  unsigned short* Wtq   = Wt4;
  unsigned short* Wtk   = Wtq + 512 * 512;
  unsigned short* Wtv   = Wtk + 512 * 512;
  unsigned short* Wtf   = Wtv + 512 * 512;
  unsigned short* Pbuf  = (unsigned short*)(ws + 6 * SZB + 4 * (size_t)512 * 512 * 2);
  float*          rowsum = (float*)((char*)Pbuf + SZP);

  hipMemsetAsync(rowsum, 0, SZR, stream);

  cvt_bf16_kernel<<<8192, 256, 0, stream>>>(rep, repb, rep1, rep1b);
  wtrans_kernel<<<dim3(8, 8, 4), 256, 0, stream>>>(Wq_w, Wk_w, Wv_w, FC_w, Wt4);

  // projections: [16384,512] x [512,512]^T
  gemm_nt<1, CH, CH, CH, CH><<<dim3(4, 128, 1), 256, 0, stream>>>(repb, 0, Wtq, 0, Wq_b,
                                                                  nullptr, 0, Qb, 0);
  gemm_nt<1, CH, CH, CH, CH><<<dim3(4, 128, 1), 256, 0, stream>>>(rep1b, 0, Wtk, 0, Wk_b,
                                                                  nullptr, 0, Kbuf, 0);
  gemm_nt<1, CH, CH, CH, CH><<<dim3(4, 128, 1), 256, 0, stream>>>(rep1b, 0, Wtv, 0, Wv_b,
                                                                  nullptr, 0, Vbuf, 0);

  vtrans_kernel<<<dim3(8, 32, 8), 256, 0, stream>>>(Vbuf, Vtb);

  // P = exp(Q K^T / sqrt(C)) per batch: [2048,512] x [2048,512]^T -> [2048,2048]
  gemm_nt<2, CH, CH, SEQ, CH><<<dim3(16, 16, 8), 256, 0, stream>>>(
      Qb, (long)SEQ * CH, Kbuf, (long)SEQ * CH, nullptr, rowsum, SEQ,
      Pbuf, (long)SEQ * SEQ);

  // O = (P / rowsum) V: [2048,2048] x Vt[512,2048]^T -> [2048,512]  (O -> Vbuf, V dead)
  gemm_nt<3, SEQ, SEQ, CH, SEQ><<<dim3(4, 16, 8), 256, 0, stream>>>(
      Pbuf, (long)SEQ * SEQ, Vtb, (long)CH * SEQ, nullptr, rowsum, SEQ,
      Vbuf, (long)SEQ * CH);

  // FC + relu -> fp32 out
  gemm_nt<0, CH, CH, CH, CH><<<dim3(4, 128, 1), 256, 0, stream>>>(Vbuf, 0, Wtf, 0, FC_b,
                                                                  nullptr, 0, out, 0);
}

// Round 4
// 317.669 us; speedup vs baseline: 3.4967x; 1.0222x over previous
//
#include <hip/hip_runtime.h>

// Fused attention block: q/k/v = relu(X W + b); A = softmax(qk^T/sqrt(C)); out = relu((A v) FC + b)
// B=8, Lq=Lk=2048, C1=C=512.  All matmuls via bf16 16x16x32 MFMA, fp32 accumulate.
// R3->R4: BK=64 (half the barriers; 32 MFMA/barrier) with XOR-swizzled glds source
// addresses so frag ds_read_b128 is 2-way (free) instead of 16-way; all epilogues
// routed through per-wave LDS patches -> coalesced 16B stores (was 64 scalar stores).

typedef __attribute__((ext_vector_type(8))) short short8;  // 8 bf16 (4 VGPRs)
typedef __attribute__((ext_vector_type(4))) float f32x4;

#define SEQ 2048
#define CH 512
#define NB 8
#define MTOT (NB * SEQ)   // 16384

// async global->LDS, 16B/lane; LDS dest = wave-uniform base + lane*16 (m104/m108)
#define GLDS16(gp, lp)                                                                  \
  __builtin_amdgcn_global_load_lds((const __attribute__((address_space(1))) void*)(gp), \
                                   (__attribute__((address_space(3))) void*)(lp), 16, 0, 0)

__device__ __forceinline__ unsigned short f2bf(float f) {  // fp32 -> bf16 RNE
  unsigned u = __float_as_uint(f);
  u += 0x7fffu + ((u >> 16) & 1u);
  return (unsigned short)(u >> 16);
}

// ---------------- fp32 -> bf16 elementwise: rep (4096 blocks) then rep1 ----------------
__global__ void cvt_bf16_kernel(const float* __restrict__ in0, unsigned short* __restrict__ out0,
                                const float* __restrict__ in1, unsigned short* __restrict__ out1) {
  int blk = blockIdx.x;
  const float* in = (blk < 4096) ? in0 : in1;
  unsigned short* out = (blk < 4096) ? out0 : out1;
  blk &= 4095;
  long i = ((long)blk * 256 + threadIdx.x) * 8;
  float4 a = *(const float4*)(in + i);
  float4 b = *(const float4*)(in + i + 4);
  ushort4 o0, o1;
  o0.x = f2bf(a.x); o0.y = f2bf(a.y); o0.z = f2bf(a.z); o0.w = f2bf(a.w);
  o1.x = f2bf(b.x); o1.y = f2bf(b.y); o1.z = f2bf(b.z); o1.w = f2bf(b.w);
  *(ushort4*)(out + i) = o0;
  *(ushort4*)(out + i + 4) = o1;
}

// ---------------- W[k][n] fp32 -> Wt[n][k] bf16, 4 weights in one dispatch ----------------
__global__ __launch_bounds__(256) void wtrans_kernel(const float* __restrict__ W0,
                                                     const float* __restrict__ W1,
                                                     const float* __restrict__ W2,
                                                     const float* __restrict__ W3,
                                                     unsigned short* __restrict__ Wt) {
  __shared__ __attribute__((aligned(16))) unsigned short tile[64 * 72];
  const int z = blockIdx.z;
  const float* W = (z == 0) ? W0 : (z == 1) ? W1 : (z == 2) ? W2 : W3;
  unsigned short* Wtz = Wt + (long)z * 512 * 512;
  const int t = threadIdx.x;
  const int k0 = blockIdx.y * 64, n0 = blockIdx.x * 64;
  const int r = t >> 4, cq = (t & 15) * 4;
#pragma unroll
  for (int j = 0; j < 4; ++j) {
    int row = r + 16 * j;  // k index
    float4 v = *(const float4*)&W[(long)(k0 + row) * 512 + n0 + cq];
    tile[row * 72 + cq + 0] = f2bf(v.x);
    tile[row * 72 + cq + 1] = f2bf(v.y);
    tile[row * 72 + cq + 2] = f2bf(v.z);
    tile[row * 72 + cq + 3] = f2bf(v.w);
  }
  __syncthreads();
#pragma unroll
  for (int j = 0; j < 4; ++j) {
    int row = r + 16 * j;  // n index
    ushort4 o;
    o.x = tile[(cq + 0) * 72 + row];
    o.y = tile[(cq + 1) * 72 + row];
    o.z = tile[(cq + 2) * 72 + row];
    o.w = tile[(cq + 3) * 72 + row];
    *(ushort4*)&Wtz[(long)(n0 + row) * 512 + k0 + cq] = o;
  }
}

// ---------------- V[b*2048+k][d] bf16 -> Vt[b][d][k] bf16 ----------------
__global__ __launch_bounds__(256) void vtrans_kernel(const unsigned short* __restrict__ V,
                                                     unsigned short* __restrict__ Vt) {
  __shared__ __attribute__((aligned(16))) unsigned short tile[64 * 72];
  const int t = threadIdx.x;
  const int b = blockIdx.z;
  const int kk0 = blockIdx.y * 64;  // seq
  const int d0 = blockIdx.x * 64;   // channel
  const unsigned short* Vb = V + (long)b * SEQ * CH;
  unsigned short* Vtb = Vt + (long)b * CH * SEQ;
  const int r = t >> 4, cq = (t & 15) * 4;
#pragma unroll
  for (int j = 0; j < 4; ++j) {
    int row = r + 16 * j;  // k index
    ushort4 v = *(const ushort4*)&Vb[(long)(kk0 + row) * CH + d0 + cq];
    tile[row * 72 + cq + 0] = v.x;
    tile[row * 72 + cq + 1] = v.y;
    tile[row * 72 + cq + 2] = v.z;
    tile[row * 72 + cq + 3] = v.w;
  }
  __syncthreads();
#pragma unroll
  for (int j = 0; j < 4; ++j) {
    int row = r + 16 * j;  // d index
    ushort4 o;
    o.x = tile[(cq + 0) * 72 + row];
    o.y = tile[(cq + 1) * 72 + row];
    o.z = tile[(cq + 2) * 72 + row];
    o.w = tile[(cq + 3) * 72 + row];
    *(ushort4*)&Vtb[(long)(d0 + row) * SEQ + kk0 + cq] = o;
  }
}

// ---------------- Generic batched NT GEMM, 128x128 tile, 4 waves, BK=64 ----------------
// out[m][n] = EPI(sum_k A[m][k] * Bt[n][k])
// EPI 0: relu(acc+bias[n]) -> fp32     (FC)
// EPI 1: relu(acc+bias[n]) -> bf16     (q/k/v projections)
// EPI 2: exp2(acc*scale)   -> bf16 P, rowsum[m] += sum_n p  (QK^T)
// EPI 3: acc / rowsum[m]   -> bf16     (P.V)
// Staging: global_load_lds dwordx4 into [128 rows][64 k] with per-lane XOR source
// swizzle (chunk ^= row&7) so frag ds_read_b128 hits 32 banks (2-way, free).
// Epilogue: C-layout fragments -> per-wave LDS patch -> coalesced 16B stores.
template <int EPI, int LDA, int LDB, int LDO, int K>
__global__ __launch_bounds__(256) void gemm_nt(const unsigned short* __restrict__ A, long sAb,
                                               const unsigned short* __restrict__ Bt, long sBb,
                                               const float* __restrict__ bias,
                                               float* __restrict__ rowsum, long sRb,
                                               void* __restrict__ outp, long sOb) {
  __shared__ __attribute__((aligned(16))) unsigned short Al[128 * 64];
  __shared__ __attribute__((aligned(16))) unsigned short Bl[128 * 64];
  const int t = threadIdx.x;
  const int w = t >> 6, l = t & 63;
  const int wr = w >> 1, wc = w & 1;
  const int lr = l & 15, lg = l >> 4;
  const int bz = blockIdx.z;
  const long m0 = (long)blockIdx.y * 128, n0 = (long)blockIdx.x * 128;
  // staging: wave w stages A/B rows [32w,32w+32), 8 rows per glds (8 lanes x 16B per row),
  // lane l loads global k-chunk ((l&7) ^ (l>>3)) into LDS chunk (l&7)  [row&7 == l>>3]
  const int srow = 32 * w + (l >> 3);
  const int sxor = ((l & 7) ^ (l >> 3)) * 8;
  const unsigned short* ga = A + bz * sAb + (long)(m0 + srow) * LDA + sxor;
  const unsigned short* gb = Bt + bz * sBb + (long)(n0 + srow) * LDB + sxor;
  unsigned short* la = &Al[32 * w * 64];  // wave-uniform LDS bases
  unsigned short* lb = &Bl[32 * w * 64];

  f32x4 acc[4][4] = {};
  for (int k0 = 0; k0 < K; k0 += 64) {
#pragma unroll
    for (int j = 0; j < 4; ++j) {
      GLDS16(ga + (long)8 * j * LDA, la + j * 512);
      GLDS16(gb + (long)8 * j * LDB, lb + j * 512);
    }
    ga += 64; gb += 64;
    __syncthreads();
#pragma unroll
    for (int h = 0; h < 2; ++h) {
      short8 af[4], bfr[4];
#pragma unroll
      for (int i = 0; i < 4; ++i) {
        const int kc = ((h * 4 + lg) ^ (lr & 7)) * 8;  // swizzled chunk
        af[i]  = *(short8*)&Al[(64 * wr + 16 * i + lr) * 64 + kc];
        bfr[i] = *(short8*)&Bl[(64 * wc + 16 * i + lr) * 64 + kc];
      }
#pragma unroll
      for (int mi = 0; mi < 4; ++mi)
#pragma unroll
        for (int ni = 0; ni < 4; ++ni)
          acc[mi][ni] =
              __builtin_amdgcn_mfma_f32_16x16x32_bf16(af[mi], bfr[ni], acc[mi][ni], 0, 0, 0);
    }
    __syncthreads();
  }

  if (EPI == 0) {
    // fp32 out via LDS patch: 16x64 floats per wave (waves 0,1 in Al; 2,3 in Bl)
    float* patchF = (float*)(w < 2 ? Al : Bl) + (w & 1) * 1024;
    float* O = (float*)outp + bz * sOb;
    float bv[4];
#pragma unroll
    for (int ni = 0; ni < 4; ++ni) bv[ni] = bias[n0 + 64 * wc + 16 * ni + lr];
#pragma unroll
    for (int mi = 0; mi < 4; ++mi) {
      const long rowb = m0 + 64 * wr + 16 * mi;
#pragma unroll
      for (int ni = 0; ni < 4; ++ni)
#pragma unroll
        for (int r = 0; r < 4; ++r)
          patchF[(lg * 4 + r) * 64 + 16 * ni + lr] = fmaxf(acc[mi][ni][r] + bv[ni], 0.0f);
      __syncthreads();
#pragma unroll
      for (int j = 0; j < 4; ++j) {
        float4 x = *(float4*)&patchF[(4 * j + (l >> 4)) * 64 + (l & 15) * 4];
        *(float4*)&O[(rowb + 4 * j + (l >> 4)) * LDO + n0 + 64 * wc + (l & 15) * 4] = x;
      }
      __syncthreads();
    }
  } else {
    // bf16 out via LDS patch: 16 rows x 72 (pad) bf16 per wave, all in Al
    unsigned short* patch = &Al[w * 16 * 72];
    unsigned short* O = (unsigned short*)outp + bz * sOb;
    float bv[4];
    if (EPI == 1) {
#pragma unroll
      for (int ni = 0; ni < 4; ++ni) bv[ni] = bias[n0 + 64 * wc + 16 * ni + lr];
    }
    float rsum[4][4] = {};
    const float* rsin = (EPI == 3) ? rowsum + bz * sRb : nullptr;
#pragma unroll
    for (int mi = 0; mi < 4; ++mi) {
      const long rowb = m0 + 64 * wr + 16 * mi;
      float invr[4];
      if (EPI == 3) {
#pragma unroll
        for (int r = 0; r < 4; ++r) invr[r] = 1.0f / rsin[rowb + lg * 4 + r];
      }
#pragma unroll
      for (int ni = 0; ni < 4; ++ni)
#pragma unroll
        for (int r = 0; r < 4; ++r) {
          float a = acc[mi][ni][r];
          unsigned short ob;
          if (EPI == 1) {
            ob = f2bf(fmaxf(a + bv[ni], 0.0f));
          } else if (EPI == 2) {
            float p = exp2f(a * 0.06375872f);  // (1/sqrt(512))*log2(e)
            ob = f2bf(p);
            rsum[mi][r] += __uint_as_float((unsigned)ob << 16);  // sum what PV will see
          } else {
            ob = f2bf(a * invr[r]);
          }
          patch[(lg * 4 + r) * 72 + 16 * ni + lr] = ob;
        }
      __syncthreads();
#pragma unroll
      for (int j = 0; j < 2; ++j) {
        short8 x = *(short8*)&patch[(l >> 2) * 72 + j * 32 + (l & 3) * 8];
        *(short8*)&O[(rowb + (l >> 2)) * LDO + n0 + 64 * wc + j * 32 + (l & 3) * 8] = x;
      }
      __syncthreads();
    }
    if (EPI == 2) {
      float* rs = rowsum + bz * sRb;
#pragma unroll
      for (int off = 1; off < 16; off <<= 1)
#pragma unroll
        for (int mi = 0; mi < 4; ++mi)
#pragma unroll
          for (int r = 0; r < 4; ++r) rsum[mi][r] += __shfl_xor(rsum[mi][r], off);
      if (lr == 0) {
#pragma unroll
        for (int mi = 0; mi < 4; ++mi)
#pragma unroll
          for (int r = 0; r < 4; ++r)
            atomicAdd(&rs[m0 + 64 * wr + 16 * mi + lg * 4 + r], rsum[mi][r]);
      }
    }
  }
}

extern "C" void kernel_launch(void* const* d_in, const int* in_sizes, int n_in,
                              void* d_out, int out_size, void* d_ws, size_t ws_size,
                              hipStream_t stream) {
  const float* rep  = (const float*)d_in[0];
  const float* rep1 = (const float*)d_in[1];
  const float* Wq_w = (const float*)d_in[2];
  const float* Wq_b = (const float*)d_in[3];
  const float* Wk_w = (const float*)d_in[4];
  const float* Wk_b = (const float*)d_in[5];
  const float* Wv_w = (const float*)d_in[6];
  const float* Wv_b = (const float*)d_in[7];
  const float* FC_w = (const float*)d_in[8];
  const float* FC_b = (const float*)d_in[9];
  float* out = (float*)d_out;
  char* ws = (char*)d_ws;

  const size_t SZB = (size_t)MTOT * CH * 2;             // 16 MiB bf16 [16384][512]
  const size_t SZP = (size_t)NB * SEQ * SEQ * 2;        // 64 MiB bf16 P
  const size_t SZR = (size_t)MTOT * 4;                  // 64 KiB rowsum
  const size_t need = 6 * SZB + 4 * (size_t)512 * 512 * 2 + SZP + SZR;
  if (ws_size < need) return;  // visible failure rather than OOB scribble

  unsigned short* Qb    = (unsigned short*)(ws + 0 * SZB);
  unsigned short* Kbuf  = (unsigned short*)(ws + 1 * SZB);
  unsigned short* Vbuf  = (unsigned short*)(ws + 2 * SZB);  // reused as attn O after vtrans
  unsigned short* Vtb   = (unsigned short*)(ws + 3 * SZB);
  unsigned short* repb  = (unsigned short*)(ws + 4 * SZB);
  unsigned short* rep1b = (unsigned short*)(ws + 5 * SZB);
  unsigned short* Wt4   = (unsigned short*)(ws + 6 * SZB);  // Wtq|Wtk|Wtv|Wtf
  unsigned short* Wtq   = Wt4;
  unsigned short* Wtk   = Wtq + 512 * 512;
  unsigned short* Wtv   = Wtk + 512 * 512;
  unsigned short* Wtf   = Wtv + 512 * 512;
  unsigned short* Pbuf  = (unsigned short*)(ws + 6 * SZB + 4 * (size_t)512 * 512 * 2);
  float*          rowsum = (float*)((char*)Pbuf + SZP);

  hipMemsetAsync(rowsum, 0, SZR, stream);

  cvt_bf16_kernel<<<8192, 256, 0, stream>>>(rep, repb, rep1, rep1b);
  wtrans_kernel<<<dim3(8, 8, 4), 256, 0, stream>>>(Wq_w, Wk_w, Wv_w, FC_w, Wt4);

  // projections: [16384,512] x [512,512]^T
  gemm_nt<1, CH, CH, CH, CH><<<dim3(4, 128, 1), 256, 0, stream>>>(repb, 0, Wtq, 0, Wq_b,
                                                                  nullptr, 0, Qb, 0);
  gemm_nt<1, CH, CH, CH, CH><<<dim3(4, 128, 1), 256, 0, stream>>>(rep1b, 0, Wtk, 0, Wk_b,
                                                                  nullptr, 0, Kbuf, 0);
  gemm_nt<1, CH, CH, CH, CH><<<dim3(4, 128, 1), 256, 0, stream>>>(rep1b, 0, Wtv, 0, Wv_b,
                                                                  nullptr, 0, Vbuf, 0);

  vtrans_kernel<<<dim3(8, 32, 8), 256, 0, stream>>>(Vbuf, Vtb);

  // P = exp(Q K^T / sqrt(C)) per batch: [2048,512] x [2048,512]^T -> [2048,2048]
  gemm_nt<2, CH, CH, SEQ, CH><<<dim3(16, 16, 8), 256, 0, stream>>>(
      Qb, (long)SEQ * CH, Kbuf, (long)SEQ * CH, nullptr, rowsum, SEQ,
      Pbuf, (long)SEQ * SEQ);

  // O = (P / rowsum) V: [2048,2048] x Vt[512,2048]^T -> [2048,512]  (O -> Vbuf, V dead)
  gemm_nt<3, SEQ, SEQ, CH, SEQ><<<dim3(4, 16, 8), 256, 0, stream>>>(
      Pbuf, (long)SEQ * SEQ, Vtb, (long)CH * SEQ, nullptr, rowsum, SEQ,
      Vbuf, (long)SEQ * CH);

  // FC + relu -> fp32 out
  gemm_nt<0, CH, CH, CH, CH><<<dim3(4, 128, 1), 256, 0, stream>>>(Vbuf, 0, Wtf, 0, FC_b,
                                                                  nullptr, 0, out, 0);
}